// Round 2
// baseline (3506.834 us; speedup 1.0000x reference)
//
#include <hip/hip_runtime.h>

// EigenvalueNet: loss = mean((R@S - w*R)^2), R,S f32[8192,8192], w f32[8192,1]
// Strategy: fused bf16-MFMA GEMM (threshold is 2% of ~8192 loss; bf16 input
// quantization adds ~0.1-1 absolute -> safe), residual+reduction fused in
// epilogue, no pred materialization. No workspace use yet.

#define U_DIM 8192
#define I_DIM 8192
#define K_DIM 8192

#define BM 128
#define BN 128
#define BK 32
#define LDA 40   // ushorts per As row (32 + 8 pad)
#define LDB 40   // ushorts per Bs row (transposed [n][k], 32 + 8 pad)

typedef __attribute__((ext_vector_type(8))) short bf16x8;
typedef __attribute__((ext_vector_type(4))) float f32x4;

__device__ __forceinline__ unsigned int bf16_rne_bits(float x) {
    // f32 -> bf16 round-nearest-even, result in low 16 bits (normal inputs)
    unsigned int u = __builtin_bit_cast(unsigned int, x);
    return (u + 0x7fffu + ((u >> 16) & 1u)) >> 16;
}

__device__ __forceinline__ unsigned int pk2(float x, float y) {
    // two f32 -> packed bf16 pair (RNE), low half = x
    return bf16_rne_bits(x) | (bf16_rne_bits(y) << 16);
}

__global__ void zero_out_kernel(float* out) { out[0] = 0.0f; }

__global__ __launch_bounds__(256) void fused_loss_kernel(
    const float* __restrict__ R, const float* __restrict__ S,
    const float* __restrict__ W, float* __restrict__ out)
{
    __shared__ unsigned short As[BM * LDA];   // [m][k] bf16 bits
    __shared__ unsigned short Bs[BN * LDB];   // [n][k] bf16 bits (transposed)
    __shared__ float wavesum[4];

    const int tid  = threadIdx.x;
    const int lane = tid & 63;
    const int wave = tid >> 6;
    const int wm   = wave >> 1;   // wave row (0..1)
    const int wn   = wave & 1;    // wave col (0..1)
    const int q    = lane >> 4;   // quad 0..3
    const int l16  = lane & 15;

    // 8x8 supertile swizzle: 64 consecutive blocks form an 8x8 square ->
    // working set 8 A-panels + 8 B-panels (64MB fp32) for LLC reuse.
    const int bid = blockIdx.x;
    const int sq  = bid >> 6;
    const int w64 = bid & 63;
    const int br  = (sq >> 3) * 8 + (w64 >> 3);
    const int bc  = (sq & 7) * 8 + (w64 & 7);
    const int row0 = br * BM;
    const int col0 = bc * BN;

    // A staging: thread covers rows {ra, ra+64}, cols ca..ca+7 of the 128x32 tile
    const int ra = tid >> 2;
    const int ca = (tid & 3) * 8;
    const float* gA = R + (size_t)(row0 + ra) * (size_t)K_DIM + ca;

    // B staging: thread covers k {kb2, kb2+1}, n nb..nb+7 of the 32x128 tile
    const int kb2 = (tid & 15) * 2;
    const int nb  = (tid >> 4) * 8;
    const float* gB = S + (size_t)kb2 * (size_t)I_DIM + col0 + nb;

    f32x4 acc[4][4];
    #pragma unroll
    for (int i = 0; i < 4; i++)
        #pragma unroll
        for (int j = 0; j < 4; j++)
            acc[i][j] = (f32x4){0.f, 0.f, 0.f, 0.f};

    for (int k0 = 0; k0 < K_DIM; k0 += BK) {
        // ---- global fp32 loads (coalesced float4) ----
        const float4 a0 = *(const float4*)(gA);
        const float4 a1 = *(const float4*)(gA + 4);
        const float4 a2 = *(const float4*)(gA + (size_t)64 * K_DIM);
        const float4 a3 = *(const float4*)(gA + (size_t)64 * K_DIM + 4);
        const float4 b0 = *(const float4*)(gB);
        const float4 b1 = *(const float4*)(gB + 4);
        const float4 b2 = *(const float4*)(gB + I_DIM);
        const float4 b3 = *(const float4*)(gB + I_DIM + 4);
        gA += BK;
        gB += (size_t)BK * I_DIM;

        __syncthreads();   // prior iteration's LDS reads complete

        // ---- A tile: convert + contiguous b128 writes ----
        uint4 wa0; wa0.x = pk2(a0.x, a0.y); wa0.y = pk2(a0.z, a0.w);
                   wa0.z = pk2(a1.x, a1.y); wa0.w = pk2(a1.z, a1.w);
        *(uint4*)&As[ra * LDA + ca] = wa0;
        uint4 wa1; wa1.x = pk2(a2.x, a2.y); wa1.y = pk2(a2.z, a2.w);
                   wa1.z = pk2(a3.x, a3.y); wa1.w = pk2(a3.z, a3.w);
        *(uint4*)&As[(ra + 64) * LDA + ca] = wa1;

        // ---- B tile: transpose via paired-k b32 writes ----
        float r0[8] = {b0.x, b0.y, b0.z, b0.w, b1.x, b1.y, b1.z, b1.w};
        float r1[8] = {b2.x, b2.y, b2.z, b2.w, b3.x, b3.y, b3.z, b3.w};
        #pragma unroll
        for (int e = 0; e < 8; e++) {
            *(unsigned int*)&Bs[(nb + e) * LDB + kb2] = pk2(r0[e], r1[e]);
        }
        __syncthreads();

        // ---- MFMA: 4x4 tiles of 16x16x32 per wave ----
        bf16x8 af[4], bfr[4];
        #pragma unroll
        for (int i = 0; i < 4; i++)
            af[i] = *(const bf16x8*)&As[(wm * 64 + i * 16 + l16) * LDA + q * 8];
        #pragma unroll
        for (int j = 0; j < 4; j++)
            bfr[j] = *(const bf16x8*)&Bs[(wn * 64 + j * 16 + l16) * LDB + q * 8];
        #pragma unroll
        for (int i = 0; i < 4; i++)
            #pragma unroll
            for (int j = 0; j < 4; j++)
                acc[i][j] = __builtin_amdgcn_mfma_f32_16x16x32_bf16(
                    af[i], bfr[j], acc[i][j], 0, 0, 0);
    }

    // ---- fused epilogue: resid = pred - w*R, accumulate resid^2 ----
    // C/D layout: col = lane&15, row = quad*4 + reg (m89/m91-verified)
    float lsum = 0.0f;
    #pragma unroll
    for (int i = 0; i < 4; i++) {
        #pragma unroll
        for (int r = 0; r < 4; r++) {
            const int grow = row0 + wm * 64 + i * 16 + q * 4 + r;
            const float wv = W[grow];
            const float* Rrow = R + (size_t)grow * I_DIM + col0 + wn * 64 + l16;
            #pragma unroll
            for (int j = 0; j < 4; j++) {
                const float resid = acc[i][j][r] - wv * Rrow[j * 16];
                lsum += resid * resid;
            }
        }
    }

    // wave shuffle reduce (64 lanes), then cross-wave via LDS
    #pragma unroll
    for (int off = 32; off > 0; off >>= 1)
        lsum += __shfl_down(lsum, off);
    if (lane == 0) wavesum[wave] = lsum;
    __syncthreads();
    if (tid == 0) {
        const float bs = wavesum[0] + wavesum[1] + wavesum[2] + wavesum[3];
        atomicAdd(out, bs * (1.0f / ((float)U_DIM * (float)I_DIM)));
    }
}

extern "C" void kernel_launch(void* const* d_in, const int* in_sizes, int n_in,
                              void* d_out, int out_size, void* d_ws, size_t ws_size,
                              hipStream_t stream) {
    const float* R = (const float*)d_in[0];
    const float* S = (const float*)d_in[1];
    const float* W = (const float*)d_in[2];
    float* out = (float*)d_out;

    zero_out_kernel<<<dim3(1), dim3(1), 0, stream>>>(out);
    fused_loss_kernel<<<dim3((U_DIM / BM) * (I_DIM / BN)), dim3(256), 0, stream>>>(
        R, S, W, out);
}